// Round 5
// baseline (3264.294 us; speedup 1.0000x reference)
//
#include <hip/hip_runtime.h>

typedef __attribute__((ext_vector_type(8))) __bf16 bf16x8;
typedef __attribute__((ext_vector_type(4))) float f32x4;

#define MFMA16(a, b, c) __builtin_amdgcn_mfma_f32_16x16x32_bf16(a, b, c, 0, 0, 0)

#define T_SEQ 512
#define F_IN 32
#define H1 128
#define E2 64
#define ROWS 4          // batch rows per block

__device__ __forceinline__ float bf2f(ushort u) {
    union { uint i; float f; } v; v.i = ((uint)u) << 16; return v.f;
}
__device__ __forceinline__ ushort f2bf(float f) {
    union { float f; uint i; } v; v.f = f;
    uint r = v.i + 0x7fffu + ((v.i >> 16) & 1u);
    return (ushort)(r >> 16);
}
__device__ __forceinline__ float fast_sigmoid(float x) {
    float e = __expf(-x);
    return __builtin_amdgcn_rcpf(1.0f + e);
}
__device__ __forceinline__ float fast_tanh(float x) {
    float e = __expf(-2.0f * x);
    return 2.0f * __builtin_amdgcn_rcpf(1.0f + e) - 1.0f;
}
__device__ __forceinline__ bf16x8 load_w8(const float* p) {
    bf16x8 r;
#pragma unroll
    for (int j = 0; j < 8; ++j) r[j] = (__bf16)p[j];
    return r;
}

// Fused 2-layer LSTM, 128 blocks x 1024 threads (16 waves), 4 batch rows/blk.
//
// ROUND THEORY (latency hiding via wave count): r4 (8 waves) hit 721us =
// ~3370 cyc/step but MFMA issue floor is only ~620 cyc/SIMD; with 2
// waves/SIMD in barrier lockstep, ds_read latency + epilogue transcendental
// chain + spill reloads (WRITE_SIZE 6.4MB: L1 wf[40]=160 regs > 128 cap)
// were all exposed. This version: 16 waves, SAME total MFMA work.
//  - L1 split 8 ways: wave w owns 4 gates x units [16w,16w+16) -> 20 weight
//    frags = 80 regs: NO SPILL. 40 MFMA/wave.
//  - L2 split 4 ways (waves 8-11): 4 gates x 16 units, 24 frags = 96 regs,
//    48 MFMA/wave. Waves 12-15: x stagers only.
//  - per SIMD: 2 L1 + 1 L2 + 1 stager wave = 128 MFMA (unchanged floor),
//    but 4-way wave interleave hides per-wave latency.
//  - epilogue: exactly 1 state update per lane (unit = w*16+l15, row = quad).
//  - same broadcast A-reads, same strides (0 conflicts), same op order
//    per output -> bit-identical results to r4.
__global__ __launch_bounds__(1024, 1) void lstm_fused(
    const float* __restrict__ x,      // [512][512][32]
    const float* __restrict__ Wih1,   // [512][32]
    const float* __restrict__ Whh1,   // [512][128]
    const float* __restrict__ bih1,   // [512]
    const float* __restrict__ bhh1,   // [512]
    const float* __restrict__ Wih2,   // [256][128]
    const float* __restrict__ Whh2,   // [256][64]
    const float* __restrict__ bih2,   // [256]
    const float* __restrict__ bhh2,   // [256]
    float* __restrict__ out)          // [512][64] fp32
{
    __shared__ __align__(16) ushort xs [2][ROWS][80];   // x: 0..31 hi, 32..63 lo
    __shared__ __align__(16) ushort h1s[2][ROWS][272];  // h1: 0..127 hi, 128..255 lo
    __shared__ __align__(16) ushort h2s[2][ROWS][144];  // h2: 0..63 hi, 64..127 lo

    const int tid  = threadIdx.x;
    const int wave = tid >> 6;
    const int lane = tid & 63;
    const int l15  = lane & 15;
    const int quad = lane >> 4;
    const int arow = l15 >> 2;        // broadcast A-row (batch row) for ds_reads
    const int r0   = blockIdx.x * ROWS;
    const bool isL1 = (wave < 8);
    const bool isL2 = (wave >= 8 && wave < 12);

    // Unified weight fragment file (disjoint per role):
    //  L1 (wave 0..7):  wf[g*4+kt] = Whh1 frag, wf[16+g] = Wih1 frag (20 used)
    //  L2 (wave 8..11): wf[g*4+kt] = Wih2 frag, wf[16+g*2+kc] = Whh2 (24 used)
    bf16x8 wf[24];
    float  bias[4];

    if (isL1) {
#pragma unroll
        for (int g = 0; g < 4; ++g) {
            const int n = g * 128 + wave * 16 + l15;
#pragma unroll
            for (int kt = 0; kt < 4; ++kt)
                wf[g * 4 + kt] = load_w8(Whh1 + n * H1 + kt * 32 + quad * 8);
            wf[16 + g] = load_w8(Wih1 + n * F_IN + quad * 8);
            bias[g] = bih1[n] + bhh1[n];
        }
    } else if (isL2) {
        const int w2 = wave - 8;
#pragma unroll
        for (int g = 0; g < 4; ++g) {
            const int n = g * 64 + w2 * 16 + l15;
#pragma unroll
            for (int kt = 0; kt < 4; ++kt)
                wf[g * 4 + kt] = load_w8(Wih2 + n * H1 + kt * 32 + quad * 8);
#pragma unroll
            for (int kc = 0; kc < 2; ++kc)
                wf[16 + g * 2 + kc] = load_w8(Whh2 + n * E2 + kc * 32 + quad * 8);
            bias[g] = bih2[n] + bhh2[n];
        }
    }

    // zero both h-state buffers
    for (int i = tid; i < 2 * ROWS * 272; i += 1024) ((ushort*)h1s)[i] = 0;
    for (int i = tid; i < 2 * ROWS * 144; i += 1024) ((ushort*)h2s)[i] = 0;

    // cell state: lane (quad,l15) of wave w owns (row=quad, unit=w*16+l15)
    float cst = 0.0f;

    // x staging: threads 768..895 own (xrow = sid>>5 in 0..3, xcol = sid&31)
    const int sid  = tid - 768;
    const int xrow = (sid >> 5) & 3, xcol = sid & 31;
    const bool stager = (tid >= 768 && tid < 896);
    const float* xptr = x + ((size_t)(r0 + xrow) * T_SEQ) * F_IN + xcol;
    float xreg = 0.0f;
    if (stager) {
        const float x0 = xptr[0];
        const ushort h = f2bf(x0);
        xs[0][xrow][xcol]      = h;
        xs[0][xrow][32 + xcol] = f2bf(x0 - bf2f(h));
        xreg = xptr[F_IN];            // x(1)
    }
    __syncthreads();

    f32x4 acc[4];

#pragma unroll 1
    for (int tt = 0; tt <= T_SEQ; ++tt) {
        const int p  = tt & 1;
        const int pn = p ^ 1;

        if (isL1) {
            if (tt < T_SEQ) {
                // ---- L1 GEMM: 4 gates x 16 units, K = 64(x) + 256(h1) ----
#pragma unroll
                for (int g = 0; g < 4; ++g)
                    acc[g] = (f32x4){bias[g], bias[g], bias[g], bias[g]};
#pragma unroll
                for (int xt = 0; xt < 2; ++xt) {       // x hi, lo (same frag)
                    const bf16x8 ax = *(const bf16x8*)&xs[p][arow][xt * 32 + quad * 8];
#pragma unroll
                    for (int g = 0; g < 4; ++g)
                        acc[g] = MFMA16(ax, wf[16 + g], acc[g]);
                }
#pragma unroll
                for (int kt = 0; kt < 8; ++kt) {       // h1 hi (0-3), lo (4-7)
                    const bf16x8 a = *(const bf16x8*)&h1s[p][arow][kt * 32 + quad * 8];
#pragma unroll
                    for (int g = 0; g < 4; ++g)
                        acc[g] = MFMA16(a, wf[g * 4 + (kt & 3)], acc[g]);
                }
                // ---- L1 epilogue, in-register: 1 update per lane ----
                const int u = wave * 16 + l15;
                const float iv = fast_sigmoid(acc[0][0]);
                const float fv = fast_sigmoid(acc[1][0]);
                const float gv = fast_tanh   (acc[2][0]);
                const float ov = fast_sigmoid(acc[3][0]);
                const float cn = fv * cst + iv * gv;
                cst = cn;
                const float h = ov * fast_tanh(cn);
                const ushort hi = f2bf(h);
                h1s[pn][quad][u]       = hi;
                h1s[pn][quad][128 + u] = f2bf(h - bf2f(hi));
            }
        } else if (isL2) {
            if (tt >= 1) {
                // ---- L2 GEMM: 4 gates x 16 units, K = 256(h1) + 128(h2) ----
#pragma unroll
                for (int g = 0; g < 4; ++g)
                    acc[g] = (f32x4){bias[g], bias[g], bias[g], bias[g]};
#pragma unroll
                for (int kt = 0; kt < 8; ++kt) {       // h1 hi+lo
                    const bf16x8 a = *(const bf16x8*)&h1s[p][arow][kt * 32 + quad * 8];
#pragma unroll
                    for (int g = 0; g < 4; ++g)
                        acc[g] = MFMA16(a, wf[g * 4 + (kt & 3)], acc[g]);
                }
#pragma unroll
                for (int kt = 0; kt < 4; ++kt) {       // h2 hi (0-1), lo (2-3)
                    const bf16x8 a = *(const bf16x8*)&h2s[p][arow][kt * 32 + quad * 8];
#pragma unroll
                    for (int g = 0; g < 4; ++g)
                        acc[g] = MFMA16(a, wf[16 + g * 2 + (kt & 1)], acc[g]);
                }
                // ---- L2 epilogue, in-register: 1 update per lane ----
                const int u = (wave - 8) * 16 + l15;
                const float iv = fast_sigmoid(acc[0][0]);
                const float fv = fast_sigmoid(acc[1][0]);
                const float gv = fast_tanh   (acc[2][0]);
                const float ov = fast_sigmoid(acc[3][0]);
                const float cn = fv * cst + iv * gv;
                cst = cn;
                const float h = ov * fast_tanh(cn);
                if (tt == T_SEQ) {
                    out[(size_t)(r0 + quad) * E2 + u] = h;
                } else {
                    const ushort hi = f2bf(h);
                    h2s[pn][quad][u]      = hi;
                    h2s[pn][quad][64 + u] = f2bf(h - bf2f(hi));
                }
            }
        } else {
            // ---- x staging: write x(tt+1) into xs[pn], prefetch x(tt+2) ----
            if (stager && tt + 1 < T_SEQ) {
                const ushort h = f2bf(xreg);
                xs[pn][xrow][xcol]      = h;
                xs[pn][xrow][32 + xcol] = f2bf(xreg - bf2f(h));
                if (tt + 2 < T_SEQ) xreg = xptr[(size_t)(tt + 2) * F_IN];
            }
        }
        __syncthreads();   // single barrier: buf pn complete, buf p reads done
    }
}

extern "C" void kernel_launch(void* const* d_in, const int* in_sizes, int n_in,
                              void* d_out, int out_size, void* d_ws, size_t ws_size,
                              hipStream_t stream) {
    lstm_fused<<<128, 1024, 0, stream>>>(
        (const float*)d_in[0], (const float*)d_in[1], (const float*)d_in[2],
        (const float*)d_in[3], (const float*)d_in[4], (const float*)d_in[5],
        (const float*)d_in[6], (const float*)d_in[7], (const float*)d_in[8],
        (float*)d_out);
}

// Round 6
// 739.580 us; speedup vs baseline: 4.4137x; 4.4137x over previous
//
#include <hip/hip_runtime.h>

typedef __attribute__((ext_vector_type(8))) __bf16 bf16x8;
typedef __attribute__((ext_vector_type(4))) float f32x4;

#define MFMA16(a, b, c) __builtin_amdgcn_mfma_f32_16x16x32_bf16(a, b, c, 0, 0, 0)

#define T_SEQ 512
#define F_IN 32
#define H1 128
#define E2 64
#define ROWS 4          // batch rows per block

__device__ __forceinline__ float bf2f(ushort u) {
    union { uint i; float f; } v; v.i = ((uint)u) << 16; return v.f;
}
__device__ __forceinline__ ushort f2bf(float f) {
    union { float f; uint i; } v; v.f = f;
    uint r = v.i + 0x7fffu + ((v.i >> 16) & 1u);
    return (ushort)(r >> 16);
}
__device__ __forceinline__ float fast_sigmoid(float x) {
    float e = __expf(-x);
    return __builtin_amdgcn_rcpf(1.0f + e);
}
__device__ __forceinline__ float fast_tanh(float x) {
    float e = __expf(-2.0f * x);
    return 2.0f * __builtin_amdgcn_rcpf(1.0f + e) - 1.0f;
}
__device__ __forceinline__ bf16x8 load_w8(const float* p) {
    bf16x8 r;
#pragma unroll
    for (int j = 0; j < 8; ++j) r[j] = (__bf16)p[j];
    return r;
}

// Fused 2-layer LSTM, 128 blocks x 512 threads (8 waves), 4 batch rows/blk.
//
// ROUND THEORY (kill the per-step vmcnt drain): r4 = 3372 cyc/step =
// ~1078 MFMA busy + ~570 VALU + ~900 x-prefetch HBM drain (__syncthreads
// emits s_waitcnt vmcnt(0); the stager's x load is issued EVERY step, so
// every barrier waits a full cold-HBM latency) + skew. Register avenue is
// closed: allocator halving law (arch = budget/2: 256@1wv, 128@2wv, 64@4wv
// measured r2/r4/r5) + scratch must stay L2-resident (r5: 4wv scratch
// overflowed L2 -> HBM reloads, 3.3ms). So keep r4's 8-wave structure and:
//  - BATCH x staging: 8 timesteps per global-load burst, issued once every
//    8 steps into a 16-deep LDS ring (xs[16][4][80]); 7 of 8 barriers now
//    have empty vmcnt -> drain amortizes ~900 -> ~112 cyc/step.
//  - staging spread over all 4 L2 waves (32 lanes each, 1 batch row each).
//  - s_setprio(1) around MFMA clusters (role-diverse waves: T5 regime).
// Numerics identical to r4 (same f2bf staging path, same MFMA order).
__global__ __launch_bounds__(512, 1) void lstm_fused(
    const float* __restrict__ x,      // [512][512][32]
    const float* __restrict__ Wih1,   // [512][32]
    const float* __restrict__ Whh1,   // [512][128]
    const float* __restrict__ bih1,   // [512]
    const float* __restrict__ bhh1,   // [512]
    const float* __restrict__ Wih2,   // [256][128]
    const float* __restrict__ Whh2,   // [256][64]
    const float* __restrict__ bih2,   // [256]
    const float* __restrict__ bhh2,   // [256]
    float* __restrict__ out)          // [512][64] fp32
{
    __shared__ __align__(16) ushort xs [16][ROWS][80];  // 16-deep t ring; hi 0..31, lo 32..63
    __shared__ __align__(16) ushort h1s[2][ROWS][272];  // h1: 0..127 hi, 128..255 lo
    __shared__ __align__(16) ushort h2s[2][ROWS][144];  // h2: 0..63 hi, 64..127 lo

    const int tid  = threadIdx.x;
    const int wave = tid >> 6;
    const int lane = tid & 63;
    const int l15  = lane & 15;
    const int quad = lane >> 4;
    const int arow = l15 >> 2;        // broadcast A-row (batch row) for ds_reads
    const int r0   = blockIdx.x * ROWS;
    const bool isL1 = (wave < 4);
    const int w    = wave & 3;

    // Unified weight fragment file (disjoint per wave group):
    //  L1 (tau = g*2+uo): wf[tau*4+kt] = Whh1 frag (128), wf[32+tau] = Wih1 (32)
    //  L2 (g): wf[g*4+kt] = Wih2 frag (64), wf[16+g*2+kc] = Whh2 frag (32)
    bf16x8 wf[40];
    float  bias[8];

    if (isL1) {
#pragma unroll
        for (int g = 0; g < 4; ++g)
#pragma unroll
            for (int uo = 0; uo < 2; ++uo) {
                const int tau = g * 2 + uo;
                const int n = g * 128 + w * 32 + uo * 16 + l15;
#pragma unroll
                for (int kt = 0; kt < 4; ++kt)
                    wf[tau * 4 + kt] = load_w8(Whh1 + n * H1 + kt * 32 + quad * 8);
                wf[32 + tau] = load_w8(Wih1 + n * F_IN + quad * 8);
                bias[tau] = bih1[n] + bhh1[n];
            }
    } else {
#pragma unroll
        for (int g = 0; g < 4; ++g) {
            const int n = g * 64 + w * 16 + l15;
#pragma unroll
            for (int kt = 0; kt < 4; ++kt)
                wf[g * 4 + kt] = load_w8(Wih2 + n * H1 + kt * 32 + quad * 8);
#pragma unroll
            for (int kc = 0; kc < 2; ++kc)
                wf[16 + g * 2 + kc] = load_w8(Whh2 + n * E2 + kc * 32 + quad * 8);
            bias[g] = bih2[n] + bhh2[n];
        }
    }

    // zero both h-state buffers
    for (int i = tid; i < 2 * ROWS * 272; i += 512) ((ushort*)h1s)[i] = 0;
    for (int i = tid; i < 2 * ROWS * 144; i += 512) ((ushort*)h2s)[i] = 0;

    // cell states: lane (quad,l15) owns batch row 'quad'
    float cst[2] = {0.0f, 0.0f};      // L1: per uo; L2 uses cst[0]

    // x staging: 32 lanes of each L2 wave; wave 4+xr stages batch row xr.
    const int xrow = w;               // for L2 waves
    const int xcol = lane;            // 0..31 valid
    const bool stager = (!isL1) && (lane < 32);
    const float* xptr = x + ((size_t)(r0 + xrow) * T_SEQ) * F_IN + xcol;
    float xr8[8];
#pragma unroll
    for (int j = 0; j < 8; ++j) xr8[j] = 0.0f;
    if (stager) {
        // prologue: stage t=0..7 into slots 0..7, prefetch t=8..15 into regs
        float t0[8];
#pragma unroll
        for (int j = 0; j < 8; ++j) t0[j] = xptr[(size_t)j * F_IN];
#pragma unroll
        for (int j = 0; j < 8; ++j) {
            const ushort h = f2bf(t0[j]);
            xs[j][xrow][xcol]      = h;
            xs[j][xrow][32 + xcol] = f2bf(t0[j] - bf2f(h));
        }
#pragma unroll
        for (int j = 0; j < 8; ++j) xr8[j] = xptr[(size_t)(8 + j) * F_IN];
    }
    __syncthreads();

    f32x4 acc[8];

#pragma unroll 1
    for (int tt = 0; tt <= T_SEQ; ++tt) {
        const int p  = tt & 1;
        const int pn = p ^ 1;

        if (isL1) {
            if (tt < T_SEQ) {
                // ---- L1 GEMM: 4 gates x 32 units, K = 64(x) + 256(h1) ----
#pragma unroll
                for (int tau = 0; tau < 8; ++tau)
                    acc[tau] = (f32x4){bias[tau], bias[tau], bias[tau], bias[tau]};
                __builtin_amdgcn_s_setprio(1);
#pragma unroll
                for (int xt = 0; xt < 2; ++xt) {       // x hi, lo (same frag)
                    const bf16x8 ax = *(const bf16x8*)&xs[tt & 15][arow][xt * 32 + quad * 8];
#pragma unroll
                    for (int tau = 0; tau < 8; ++tau)
                        acc[tau] = MFMA16(ax, wf[32 + tau], acc[tau]);
                }
#pragma unroll
                for (int kt = 0; kt < 8; ++kt) {       // h1 hi (0-3), lo (4-7)
                    const bf16x8 a = *(const bf16x8*)&h1s[p][arow][kt * 32 + quad * 8];
#pragma unroll
                    for (int tau = 0; tau < 8; ++tau)
                        acc[tau] = MFMA16(a, wf[tau * 4 + (kt & 3)], acc[tau]);
                }
                __builtin_amdgcn_s_setprio(0);
                // ---- L1 epilogue, in-register, all 64 lanes ----
#pragma unroll
                for (int uo = 0; uo < 2; ++uo) {
                    const int u = w * 32 + uo * 16 + l15;
                    const float iv = fast_sigmoid(acc[0 + uo][0]);
                    const float fv = fast_sigmoid(acc[2 + uo][0]);
                    const float gv = fast_tanh   (acc[4 + uo][0]);
                    const float ov = fast_sigmoid(acc[6 + uo][0]);
                    const float cn = fv * cst[uo] + iv * gv;
                    cst[uo] = cn;
                    const float h = ov * fast_tanh(cn);
                    const ushort hi = f2bf(h);
                    h1s[pn][quad][u]       = hi;
                    h1s[pn][quad][128 + u] = f2bf(h - bf2f(hi));
                }
            }
        } else {
            if (tt >= 1) {
                // ---- L2 GEMM: 4 gates x 16 units, K = 256(h1) + 128(h2) ----
#pragma unroll
                for (int g = 0; g < 4; ++g)
                    acc[g] = (f32x4){bias[g], bias[g], bias[g], bias[g]};
                __builtin_amdgcn_s_setprio(1);
#pragma unroll
                for (int kt = 0; kt < 8; ++kt) {       // h1 hi+lo
                    const bf16x8 a = *(const bf16x8*)&h1s[p][arow][kt * 32 + quad * 8];
#pragma unroll
                    for (int g = 0; g < 4; ++g)
                        acc[g] = MFMA16(a, wf[g * 4 + (kt & 3)], acc[g]);
                }
#pragma unroll
                for (int kt = 0; kt < 4; ++kt) {       // h2 hi (0-1), lo (2-3)
                    const bf16x8 a = *(const bf16x8*)&h2s[p][arow][kt * 32 + quad * 8];
#pragma unroll
                    for (int g = 0; g < 4; ++g)
                        acc[g] = MFMA16(a, wf[16 + g * 2 + (kt & 1)], acc[g]);
                }
                __builtin_amdgcn_s_setprio(0);
                // ---- L2 epilogue, in-register, all 64 lanes ----
                const int u = w * 16 + l15;
                const float iv = fast_sigmoid(acc[0][0]);
                const float fv = fast_sigmoid(acc[1][0]);
                const float gv = fast_tanh   (acc[2][0]);
                const float ov = fast_sigmoid(acc[3][0]);
                const float cn = fv * cst[0] + iv * gv;
                cst[0] = cn;
                const float h = ov * fast_tanh(cn);
                if (tt == T_SEQ) {
                    out[(size_t)(r0 + quad) * E2 + u] = h;
                } else {
                    const ushort hi = f2bf(h);
                    h2s[pn][quad][u]      = hi;
                    h2s[pn][quad][64 + u] = f2bf(h - bf2f(hi));
                }
            }
            // ---- batched x staging, once every 8 steps ----
            // write t = tt+8..tt+15 (held in regs) to ring slots, then
            // issue loads for t = tt+16..tt+23. Only 1 of 8 barriers has
            // outstanding vmcnt.
            if (stager && (tt & 7) == 0) {
#pragma unroll
                for (int j = 0; j < 8; ++j) {
                    const int t = tt + 8 + j;
                    if (t < T_SEQ) {
                        const ushort h = f2bf(xr8[j]);
                        xs[t & 15][xrow][xcol]      = h;
                        xs[t & 15][xrow][32 + xcol] = f2bf(xr8[j] - bf2f(h));
                    }
                }
#pragma unroll
                for (int j = 0; j < 8; ++j) {
                    const int t = tt + 16 + j;
                    if (t < T_SEQ) xr8[j] = xptr[(size_t)t * F_IN];
                }
            }
        }
        __syncthreads();   // single barrier: buf pn complete, buf p reads done
    }
}

extern "C" void kernel_launch(void* const* d_in, const int* in_sizes, int n_in,
                              void* d_out, int out_size, void* d_ws, size_t ws_size,
                              hipStream_t stream) {
    lstm_fused<<<128, 512, 0, stream>>>(
        (const float*)d_in[0], (const float*)d_in[1], (const float*)d_in[2],
        (const float*)d_in[3], (const float*)d_in[4], (const float*)d_in[5],
        (const float*)d_in[6], (const float*)d_in[7], (const float*)d_in[8],
        (float*)d_out);
}